// Round 1
// baseline (57.171 us; speedup 1.0000x reference)
//
#include <hip/hip_runtime.h>
#include <math.h>

// QuantumNATHybridModel: pool(6x6) -> linear(16->4) -> 4-qubit circuit -> BatchNorm1d
// Collapse: out[b,q] = r^T A_q r, with r from per-sample RX angles and A_q a fixed
// real symmetric 16x16 matrix precomputed from qparams each launch.

#define BATCH 65536
#define SPW 8                      // samples per wave
#define MAIN_BLOCKS (BATCH / (4 * SPW))   // 2048 blocks of 256 threads (4 waves)

// ---------------------------------------------------------------------------
// Precompute kernel: build U (16x16 complex) from qparams, then A_q (4x16x16 real).
// One block of 256 threads; threads 0..15 each own a column of U.
// ---------------------------------------------------------------------------
__global__ __launch_bounds__(256) void qnat_precompute(const float* __restrict__ qp,
                                                       float* __restrict__ A) {
  __shared__ float Ur[16][17], Ui[16][17];
  const int tid = threadIdx.x;
  if (tid < 16) {
    const int col = tid;
    float ur[16], ui[16];
#pragma unroll
    for (int i = 0; i < 16; i++) { ur[i] = (i == col) ? 1.f : 0.f; ui[i] = 0.f; }
#pragma unroll
    for (int l = 0; l < 3; l++) {
#pragma unroll
      for (int q = 0; q < 4; q++) {
        const int b = 3 - q;  // qubit q lives on bit (3-q)
        const float ty = qp[(l * 4 + q) * 3 + 0];
        const float tz = qp[(l * 4 + q) * 3 + 1];
        const float cy = cosf(0.5f * ty), sy = sinf(0.5f * ty);
#pragma unroll
        for (int i0 = 0; i0 < 16; i0++) {
          if (((i0 >> b) & 1) == 0) {
            const int i1 = i0 | (1 << b);
            const float r0 = ur[i0], m0 = ui[i0], r1 = ur[i1], m1 = ui[i1];
            // RY = [[c,-s],[s,c]]
            ur[i0] = cy * r0 - sy * r1;  ui[i0] = cy * m0 - sy * m1;
            ur[i1] = sy * r0 + cy * r1;  ui[i1] = sy * m0 + cy * m1;
          }
        }
        const float cz = cosf(0.5f * tz), sz = sinf(0.5f * tz);
#pragma unroll
        for (int i0 = 0; i0 < 16; i0++) {
          if (((i0 >> b) & 1) == 0) {
            const int i1 = i0 | (1 << b);
            const float r0 = ur[i0], m0 = ui[i0], r1 = ur[i1], m1 = ui[i1];
            // RZ = diag(e^{-it/2}, e^{+it/2})
            ur[i0] = cz * r0 + sz * m0;  ui[i0] = cz * m0 - sz * r0;
            ur[i1] = cz * r1 - sz * m1;  ui[i1] = cz * m1 + sz * r1;
          }
        }
      }
      // CNOT edges (c,t): (0,1),(1,2),(2,3),(3,0); bit of qubit x is 3-x.
      const int cb[4] = {3, 2, 1, 0};
      const int tb[4] = {2, 1, 0, 3};
#pragma unroll
      for (int e = 0; e < 4; e++) {
#pragma unroll
        for (int i = 0; i < 16; i++) {
          if (((i >> cb[e]) & 1) && (((i >> tb[e]) & 1) == 0)) {
            const int j2 = i | (1 << tb[e]);
            float t0 = ur[i]; ur[i] = ur[j2]; ur[j2] = t0;
            float t1 = ui[i]; ui[i] = ui[j2]; ui[j2] = t1;
          }
        }
      }
    }
#pragma unroll
    for (int i = 0; i < 16; i++) { Ur[i][col] = ur[i]; Ui[i][col] = ui[i]; }
  }
  __syncthreads();
  // thread tid = j*16+k computes A_q[j][k] for q=0..3
  const int j = tid >> 4, k = tid & 15;
#pragma unroll
  for (int q = 0; q < 4; q++) {
    const int b = 3 - q;
    float mr = 0.f, mi = 0.f;
#pragma unroll
    for (int i = 0; i < 16; i++) {
      const float z = ((i >> b) & 1) ? -1.f : 1.f;
      const float ar = Ur[i][j], ai = Ui[i][j], br = Ur[i][k], bi = Ui[i][k];
      mr += z * (ar * br + ai * bi);   // conj(U[i][j]) * U[i][k]
      mi += z * (ar * bi - ai * br);
    }
    // A[j][k] = Re( i^{pc(j)} * (mr + i*mi) * (-i)^{pc(k)} )
    const int e = (__popc((unsigned)j) - __popc((unsigned)k)) & 3;
    const float re = (e == 0) ? mr : (e == 1) ? -mi : (e == 2) ? -mr : mi;
    A[(q << 8) + tid] = re;
  }
}

// ---------------------------------------------------------------------------
// Main kernel: one wave per sample (SPW samples sequentially per wave).
// theta_q = sum_p x[p]*enc_w[q][f(p)]/36 + enc_b[q];  out[s,q] = r^T A_q r.
// ---------------------------------------------------------------------------
__global__ __launch_bounds__(256) void qnat_main(const float* __restrict__ x,
                                                 const float* __restrict__ enc_w,
                                                 const float* __restrict__ enc_b,
                                                 const float* __restrict__ A,
                                                 float* __restrict__ out) {
  __shared__ float4 sW4[16];
  const int tid = threadIdx.x;
  if (tid < 16) {
    const float inv36 = 1.0f / 36.0f;
    sW4[tid] = make_float4(enc_w[tid] * inv36, enc_w[16 + tid] * inv36,
                           enc_w[32 + tid] * inv36, enc_w[48 + tid] * inv36);
  }
  __syncthreads();

  const int wave = tid >> 6, lane = tid & 63;
  const int j = lane & 15;        // row of A within 16-lane group
  const int g = lane >> 4;        // which qubit's A this group owns

  // per-(lane,t) fused pool+encoder weights, held in 36 VGPRs
  float4 w4[9];
#pragma unroll
  for (int t = 0; t < 9; t++) {
    const int p = lane + 64 * t;
    const int row = p / 24, colp = p - row * 24;
    const int fidx = (row / 6) * 4 + (colp / 6);
    w4[t] = sW4[fidx];
  }
  // A row for this lane's (g, j): 16 registers
  float Areg[16];
#pragma unroll
  for (int k = 0; k < 16; k++) Areg[k] = A[(g << 8) + (j << 4) + k];
  const float b0 = enc_b[0], b1 = enc_b[1], b2 = enc_b[2], b3 = enc_b[3];

  const int s0 = (blockIdx.x * 4 + wave) * SPW;

  float xv[9];
  {
    const float* xs = x + (size_t)s0 * 576 + lane;
#pragma unroll
    for (int t = 0; t < 9; t++) xv[t] = xs[64 * t];
  }

  for (int i = 0; i < SPW; i++) {
    const int s = s0 + i;
    float xn[9];
    if (i + 1 < SPW) {  // prefetch next sample (uniform branch)
      const float* xs = x + (size_t)(s + 1) * 576 + lane;
#pragma unroll
      for (int t = 0; t < 9; t++) xn[t] = xs[64 * t];
    }

    float a0 = 0.f, a1 = 0.f, a2 = 0.f, a3 = 0.f;
#pragma unroll
    for (int t = 0; t < 9; t++) {
      a0 = fmaf(xv[t], w4[t].x, a0);
      a1 = fmaf(xv[t], w4[t].y, a1);
      a2 = fmaf(xv[t], w4[t].z, a2);
      a3 = fmaf(xv[t], w4[t].w, a3);
    }
#pragma unroll
    for (int off = 32; off >= 1; off >>= 1) {
      a0 += __shfl_xor(a0, off);
      a1 += __shfl_xor(a1, off);
      a2 += __shfl_xor(a2, off);
      a3 += __shfl_xor(a3, off);
    }
    const float th0 = a0 + b0, th1 = a1 + b1, th2 = a2 + b2, th3 = a3 + b3;
    float c0, s0_, c1, s1_, c2, s2_, c3, s3_;
    __sincosf(0.5f * th0, &s0_, &c0);
    __sincosf(0.5f * th1, &s1_, &c1);
    __sincosf(0.5f * th2, &s2_, &c2);
    __sincosf(0.5f * th3, &s3_, &c3);
    // r_k = p01[k>>2] * p23[k&3]; qubit0 on bit3 ... qubit3 on bit0
    const float p01[4] = {c0 * c1, c0 * s1_, s0_ * c1, s0_ * s1_};
    const float p23[4] = {c2 * c3, c2 * s3_, s2_ * c3, s2_ * s3_};
    // inner_j = sum_k A[j][k] r_k, factored over hi/lo pairs
    float inner = 0.f;
#pragma unroll
    for (int hi = 0; hi < 4; hi++) {
      float sh = 0.f;
#pragma unroll
      for (int lo = 0; lo < 4; lo++) sh = fmaf(Areg[4 * hi + lo], p23[lo], sh);
      inner = fmaf(p01[hi], sh, inner);
    }
    const float rj = ((j & 8) ? s0_ : c0) * ((j & 4) ? s1_ : c1) *
                     ((j & 2) ? s2_ : c2) * ((j & 1) ? s3_ : c3);
    float v = inner * rj;
    v += __shfl_xor(v, 1);
    v += __shfl_xor(v, 2);
    v += __shfl_xor(v, 4);
    v += __shfl_xor(v, 8);
    if (j == 0) out[(size_t)s * 4 + g] = v;

    if (i + 1 < SPW) {
#pragma unroll
      for (int t = 0; t < 9; t++) xv[t] = xn[t];
    }
  }
}

// ---------------------------------------------------------------------------
// BatchNorm statistics: per-q sum and sum-of-squares in double.
// ---------------------------------------------------------------------------
__global__ __launch_bounds__(256) void qnat_reduce(const float* __restrict__ out,
                                                   double* __restrict__ acc) {
  const int tid = threadIdx.x;
  double s = 0.0, ss = 0.0;
  // stride (64 blocks * 256 threads) is a multiple of 4 -> each thread stays on one q
  for (size_t i = (size_t)blockIdx.x * 256 + tid; i < (size_t)BATCH * 4; i += 64 * 256) {
    const double v = (double)out[i];
    s += v;
    ss = fma(v, v, ss);
  }
#pragma unroll
  for (int off = 4; off <= 32; off <<= 1) {  // reduce lanes with same (tid&3)
    s += __shfl_xor(s, off);
    ss += __shfl_xor(ss, off);
  }
  __shared__ double sm[2][4][4];  // [s/ss][wave][q]
  const int lane = tid & 63, wave = tid >> 6;
  if (lane < 4) { sm[0][wave][lane] = s; sm[1][wave][lane] = ss; }
  __syncthreads();
  if (tid < 4) {
    const double ts = sm[0][0][tid] + sm[0][1][tid] + sm[0][2][tid] + sm[0][3][tid];
    const double tss = sm[1][0][tid] + sm[1][1][tid] + sm[1][2][tid] + sm[1][3][tid];
    atomicAdd(&acc[tid], ts);
    atomicAdd(&acc[4 + tid], tss);
  }
}

// ---------------------------------------------------------------------------
// Normalize in place: out = (raw - mean)/sqrt(var+eps)*gamma + beta
// ---------------------------------------------------------------------------
__global__ __launch_bounds__(256) void qnat_norm(float* __restrict__ out,
                                                 const double* __restrict__ acc,
                                                 const float* __restrict__ gamma,
                                                 const float* __restrict__ beta) {
  __shared__ float sMean[4], sScale[4], sBeta[4];
  const int tid = threadIdx.x;
  if (tid < 4) {
    const double n = (double)BATCH;
    const double mean = acc[tid] / n;
    const double var = acc[4 + tid] / n - mean * mean;
    const double inv = 1.0 / sqrt(var + 1e-5);
    sMean[tid] = (float)mean;
    sScale[tid] = (float)(gamma[tid] * inv);
    sBeta[tid] = beta[tid];
  }
  __syncthreads();
  const size_t i = (size_t)blockIdx.x * 256 + tid;  // 65536 float4s, 256 blocks
  float4 v = ((const float4*)out)[i];
  v.x = (v.x - sMean[0]) * sScale[0] + sBeta[0];
  v.y = (v.y - sMean[1]) * sScale[1] + sBeta[1];
  v.z = (v.z - sMean[2]) * sScale[2] + sBeta[2];
  v.w = (v.w - sMean[3]) * sScale[3] + sBeta[3];
  ((float4*)out)[i] = v;
}

extern "C" void kernel_launch(void* const* d_in, const int* in_sizes, int n_in,
                              void* d_out, int out_size, void* d_ws, size_t ws_size,
                              hipStream_t stream) {
  const float* x       = (const float*)d_in[0];
  const float* enc_w   = (const float*)d_in[1];
  const float* enc_b   = (const float*)d_in[2];
  const float* qparams = (const float*)d_in[3];
  const float* gamma   = (const float*)d_in[4];
  const float* beta    = (const float*)d_in[5];
  float* out = (float*)d_out;

  float* A = (float*)d_ws;                          // 4*16*16 floats = 4 KB
  double* acc = (double*)((char*)d_ws + 4096);      // 8 doubles

  hipMemsetAsync((char*)d_ws + 4096, 0, 8 * sizeof(double), stream);
  qnat_precompute<<<1, 256, 0, stream>>>(qparams, A);
  qnat_main<<<MAIN_BLOCKS, 256, 0, stream>>>(x, enc_w, enc_b, A, out);
  qnat_reduce<<<64, 256, 0, stream>>>(out, acc);
  qnat_norm<<<256, 256, 0, stream>>>(out, acc, gamma, beta);
}